// Round 1
// baseline (209.245 us; speedup 1.0000x reference)
//
#include <hip/hip_runtime.h>
#include <hip/hip_bf16.h>

// Problem constants (B=16, T=2048 fixed by setup_inputs)
constexpr int NB = 16;
constexpr int NT = 2048;
constexpr int KPROP = 2000;
constexpr int TIE_CAP = 8192;

// ---------------------------------------------------------------------------
// Workspace layout (bytes):
//   0    : nS[16]      (int)   -- # selected start anchors per batch
//   64   : nE[16]      (int)
//   128  : selAll[16]  (int)   -- <K valid pairs -> keep everything
//   192  : P[16]       (uint)  -- accumulated radix prefix (threshold bits)
//   256  : need[16]    (int)   -- remaining count inside current prefix
//   320  : tieCnt[16]  (int)
//   512  : hist[3][16][2048] u32  (393216 B)   [zeroed each call: first 393728 B]
//   393728: sIdx[16][2048] int
//   524800: sVal[16][2048] f32
//   655872: eIdx[16][2048] int
//   786944: eVal[16][2048] f32
//   918016: tie[16][8192] int
// total ~1.44 MB
// ---------------------------------------------------------------------------

__global__ void k_select(const float* __restrict__ start, const float* __restrict__ end,
                         int* nS, int* nE, int* sIdx, float* sVal, int* eIdx, float* eVal) {
    int b = blockIdx.x;
    int which = blockIdx.y;
    const float* p = (which == 0 ? start : end) + (size_t)b * NT;
    int* nArr = (which == 0 ? nS : nE);
    int* idxArr = (which == 0 ? sIdx : eIdx) + b * NT;
    float* valArr = (which == 0 ? sVal : eVal) + b * NT;

    __shared__ float red[256];
    float m = -1.0f;
    for (int t = threadIdx.x; t < NT; t += 256) m = fmaxf(m, p[t]);
    red[threadIdx.x] = m;
    __syncthreads();
    for (int s = 128; s > 0; s >>= 1) {
        if (threadIdx.x < s) red[threadIdx.x] = fmaxf(red[threadIdx.x], red[threadIdx.x + s]);
        __syncthreads();
    }
    float thr = 0.5f * red[0];

    for (int t = threadIdx.x; t < NT; t += 256) {
        float v = p[t];
        bool rise = (t == 0) || (v > p[t - 1]);
        bool fall = (t == NT - 1) || (v > p[t + 1]);
        if ((rise && fall) || (v > thr)) {
            int pos = atomicAdd(nArr + b, 1);
            idxArr[pos] = t;
            valArr[pos] = v;
        }
    }
}

// Histogram one radix level of the f32 score bit pattern (non-negative floats:
// bit pattern is monotonic in value). Only pairs matching the already-resolved
// prefix P participate.
__global__ void k_hist(const int* __restrict__ nS, const int* __restrict__ nE,
                       const int* __restrict__ sIdx, const float* __restrict__ sVal,
                       const int* __restrict__ eIdx, const float* __restrict__ eVal,
                       const int* __restrict__ selAll, const unsigned* __restrict__ P,
                       unsigned* __restrict__ histLevel,
                       unsigned prefMask, int shift, unsigned bucketMask) {
    int b = blockIdx.y;
    if (selAll[b]) return;
    int ns = nS[b], ne = nE[b];
    int total = ns * ne;
    unsigned pref = P[b];
    const int* si = sIdx + b * NT;
    const float* sv = sVal + b * NT;
    const int* ei = eIdx + b * NT;
    const float* ev = eVal + b * NT;
    unsigned* h = histLevel + b * 2048;

    __shared__ unsigned shist[2048];
    for (int c = threadIdx.x; c < 2048; c += 256) shist[c] = 0u;
    __syncthreads();

    int stride = gridDim.x * 256;
    for (int p = blockIdx.x * 256 + threadIdx.x; p < total; p += stride) {
        int i = p / ne;
        int j = p - i * ne;
        int s = si[i], e = ei[j];
        if (e < s) continue;
        unsigned bits = __float_as_uint(sv[i] * ev[j]);
        if ((bits & prefMask) != pref) continue;
        atomicAdd(&shist[(bits >> shift) & bucketMask], 1u);
    }
    __syncthreads();
    for (int c = threadIdx.x; c < 2048; c += 256) {
        unsigned v = shist[c];
        if (v) atomicAdd(&h[c], v);
    }
}

// Descending scan over one level's histogram: find bucket where the
// cumulative count crosses `need`, extend prefix, update need.
__global__ void k_scan(const unsigned* __restrict__ histLevel, int level, int shift,
                       int buckets, int* selAll, unsigned* P, int* need) {
    int b = blockIdx.x;
    if (level > 0 && selAll[b]) return;
    const unsigned* h = histLevel + b * 2048;

    __shared__ int chunkSum[256];
    int chunk = buckets / 256;   // 8, 8, or 4
    int base = threadIdx.x * chunk;
    int sum = 0;
    for (int c = 0; c < chunk; c++) sum += (int)h[base + c];
    chunkSum[threadIdx.x] = sum;
    __syncthreads();

    if (threadIdx.x == 0) {
        int nd = (level == 0) ? KPROP : need[b];
        int acc = 0;
        int tchunk = -1;
        for (int t = 255; t >= 0; t--) {
            if (acc + chunkSum[t] >= nd) { tchunk = t; break; }
            acc += chunkSum[t];
        }
        if (tchunk < 0) {
            // fewer than K valid pairs in total (only possible at level 0)
            selAll[b] = 1;
        } else {
            int found = -1;
            for (int c = tchunk * chunk + chunk - 1; c >= tchunk * chunk; c--) {
                int cnt = (int)h[c];
                if (acc + cnt >= nd) { found = c; break; }
                acc += cnt;
            }
            if (found < 0) { selAll[b] = 1; }   // defensive; cannot happen
            else {
                P[b] |= ((unsigned)found) << shift;
                need[b] = nd - acc;             // in [1, cnt[found]]
            }
        }
    }
}

// Write 1.0 for all pairs strictly above threshold V; collect ties (== V).
__global__ void k_scatter(const int* __restrict__ nS, const int* __restrict__ nE,
                          const int* __restrict__ sIdx, const float* __restrict__ sVal,
                          const int* __restrict__ eIdx, const float* __restrict__ eVal,
                          const int* __restrict__ selAll, const unsigned* __restrict__ P,
                          float* __restrict__ out, int* tieCnt, int* tie) {
    int b = blockIdx.y;
    int ns = nS[b], ne = nE[b];
    int total = ns * ne;
    int all = selAll[b];
    unsigned V = P[b];
    const int* si = sIdx + b * NT;
    const float* sv = sVal + b * NT;
    const int* ei = eIdx + b * NT;
    const float* ev = eVal + b * NT;

    int stride = gridDim.x * 256;
    for (int p = blockIdx.x * 256 + threadIdx.x; p < total; p += stride) {
        int i = p / ne;
        int j = p - i * ne;
        int s = si[i], e = ei[j];
        if (e < s) continue;
        unsigned bits = __float_as_uint(sv[i] * ev[j]);
        if (all || bits > V) {
            out[((size_t)b * NT + (e - s)) * NT + s] = 1.0f;
        } else if (bits == V) {
            int pos = atomicAdd(tieCnt + b, 1);
            if (pos < TIE_CAP) tie[b * TIE_CAP + pos] = s * NT + e;
        }
    }
}

// Among score == V, keep the `need` smallest flat indices (top_k tie order).
__global__ void k_ties(const int* __restrict__ selAll, const int* __restrict__ need,
                       const int* __restrict__ tieCnt, const int* __restrict__ tie,
                       float* __restrict__ out) {
    int b = blockIdx.x;
    if (selAll[b]) return;
    int n = min(tieCnt[b], TIE_CAP);
    int nd = need[b];
    const int* tl = tie + b * TIE_CAP;
    for (int k = threadIdx.x; k < n; k += blockDim.x) {
        int flat = tl[k];
        int rank = 0;
        for (int j = 0; j < n; j++) rank += (tl[j] < flat) ? 1 : 0;
        if (rank < nd) {
            int s = flat >> 11;            // NT = 2048
            int e = flat & (NT - 1);
            out[((size_t)b * NT + (e - s)) * NT + s] = 1.0f;
        }
    }
}

extern "C" void kernel_launch(void* const* d_in, const int* in_sizes, int n_in,
                              void* d_out, int out_size, void* d_ws, size_t ws_size,
                              hipStream_t stream) {
    const float* start = (const float*)d_in[0];
    const float* end   = (const float*)d_in[1];
    // d_in[2] (actionness) is unused by the reference.
    float* out = (float*)d_out;
    char* ws = (char*)d_ws;

    int*      nS     = (int*)     (ws + 0);
    int*      nE     = (int*)     (ws + 64);
    int*      selAll = (int*)     (ws + 128);
    unsigned* P      = (unsigned*)(ws + 192);
    int*      need   = (int*)     (ws + 256);
    int*      tieCnt = (int*)     (ws + 320);
    unsigned* hist   = (unsigned*)(ws + 512);
    int*      sIdx   = (int*)     (ws + 393728);
    float*    sVal   = (float*)   (ws + 524800);
    int*      eIdx   = (int*)     (ws + 655872);
    float*    eVal   = (float*)   (ws + 786944);
    int*      tie    = (int*)     (ws + 918016);

    // Zero output (268 MB) and the scalar+histogram region of the workspace.
    hipMemsetAsync(d_out, 0, (size_t)out_size * sizeof(float), stream);
    hipMemsetAsync(d_ws, 0, 393728, stream);

    // 1) anchor selection + compaction
    k_select<<<dim3(NB, 2), 256, 0, stream>>>(start, end, nS, nE, sIdx, sVal, eIdx, eVal);

    // 2) exact radix-select of the K-th score (3 levels: bits [31:21],[20:10],[9:0])
    k_hist<<<dim3(64, NB), 256, 0, stream>>>(nS, nE, sIdx, sVal, eIdx, eVal, selAll, P,
                                             hist, 0u, 21, 2047u);
    k_scan<<<NB, 256, 0, stream>>>(hist, 0, 21, 2048, selAll, P, need);

    k_hist<<<dim3(64, NB), 256, 0, stream>>>(nS, nE, sIdx, sVal, eIdx, eVal, selAll, P,
                                             hist + NB * 2048, 0xFFE00000u, 10, 2047u);
    k_scan<<<NB, 256, 0, stream>>>(hist + NB * 2048, 1, 10, 2048, selAll, P, need);

    k_hist<<<dim3(64, NB), 256, 0, stream>>>(nS, nE, sIdx, sVal, eIdx, eVal, selAll, P,
                                             hist + 2 * NB * 2048, 0xFFFFFC00u, 0, 1023u);
    k_scan<<<NB, 256, 0, stream>>>(hist + 2 * NB * 2048, 2, 0, 1024, selAll, P, need);

    // 3) scatter winners; collect threshold ties
    k_scatter<<<dim3(64, NB), 256, 0, stream>>>(nS, nE, sIdx, sVal, eIdx, eVal, selAll, P,
                                                out, tieCnt, tie);
    // 4) resolve ties by smallest flat index (matches lax.top_k tie order)
    k_ties<<<NB, 256, 0, stream>>>(selAll, need, tieCnt, tie, out);
}

// Round 2
// 179.831 us; speedup vs baseline: 1.1636x; 1.1636x over previous
//
#include <hip/hip_runtime.h>
#include <hip/hip_bf16.h>

// Problem constants (B=16, T=2048 fixed by setup_inputs)
constexpr int NB = 16;
constexpr int NT = 2048;
constexpr int KPROP = 2000;
constexpr int TIE_CAP = 8192;
constexpr int HIST_WORDS = 3 * NB * 2048;   // 98304 u32

// ---------------------------------------------------------------------------
// Workspace layout (bytes):
//   0    : nS[16]      (int)
//   64   : nE[16]      (int)
//   128  : selAll[16]  (int)
//   192  : P[16]       (uint)
//   256  : need[16]    (int)
//   320  : tieCnt[16]  (int)
//   512  : hist[3][16][2048] u32  (393216 B)
//   393728: sIdx[16][2048] int
//   524800: sVal[16][2048] f32
//   655872: eIdx[16][2048] int
//   786944: eVal[16][2048] f32
//   918016: tie[16][8192] int
// All zeroing is done in-kernel (no hipMemset): k_fill zeroes d_out,
// k_select zeroes hist + per-batch scalars.
// ---------------------------------------------------------------------------

__global__ void k_fill(float4* __restrict__ out, int n4) {
    int stride = gridDim.x * blockDim.x;
    float4 z = make_float4(0.f, 0.f, 0.f, 0.f);
    for (int i = blockIdx.x * blockDim.x + threadIdx.x; i < n4; i += stride)
        out[i] = z;
}

__global__ void k_select(const float* __restrict__ start, const float* __restrict__ end,
                         int* nS, int* nE, int* selAll, unsigned* P, int* need, int* tieCnt,
                         unsigned* hist,
                         int* sIdx, float* sVal, int* eIdx, float* eVal) {
    int b = blockIdx.x;
    int which = blockIdx.y;
    const float* p = (which == 0 ? start : end) + (size_t)b * NT;
    int* nArr = (which == 0 ? nS : nE);
    int* idxArr = (which == 0 ? sIdx : eIdx) + b * NT;
    float* valArr = (which == 0 ? sVal : eVal) + b * NT;

    // zero per-batch scalars (disjoint per block) and a slice of the hist array
    if (threadIdx.x == 0) {
        nArr[b] = 0;
        if (which == 0) { selAll[b] = 0; P[b] = 0u; need[b] = 0; tieCnt[b] = 0; }
    }
    int gid = (which * gridDim.x + b) * 256 + threadIdx.x;   // 0..8191
    for (int h = gid; h < HIST_WORDS; h += 2 * NB * 256) hist[h] = 0u;

    __shared__ float red[256];
    float m = -1.0f;
    for (int t = threadIdx.x; t < NT; t += 256) m = fmaxf(m, p[t]);
    red[threadIdx.x] = m;
    __syncthreads();
    for (int s = 128; s > 0; s >>= 1) {
        if (threadIdx.x < s) red[threadIdx.x] = fmaxf(red[threadIdx.x], red[threadIdx.x + s]);
        __syncthreads();
    }
    float thr = 0.5f * red[0];

    for (int t = threadIdx.x; t < NT; t += 256) {
        float v = p[t];
        bool rise = (t == 0) || (v > p[t - 1]);
        bool fall = (t == NT - 1) || (v > p[t + 1]);
        if ((rise && fall) || (v > thr)) {
            int pos = atomicAdd(nArr + b, 1);
            idxArr[pos] = t;
            valArr[pos] = v;
        }
    }
}

// Histogram one radix level of the f32 score bit pattern (non-negative floats:
// bit pattern is monotonic in value). Only pairs matching the already-resolved
// prefix P participate. 2D loop: start-row per block-stride, end-col per thread.
__global__ void k_hist(const int* __restrict__ nS, const int* __restrict__ nE,
                       const int* __restrict__ sIdx, const float* __restrict__ sVal,
                       const int* __restrict__ eIdx, const float* __restrict__ eVal,
                       const int* __restrict__ selAll, const unsigned* __restrict__ P,
                       unsigned* __restrict__ histLevel,
                       unsigned prefMask, int shift, unsigned bucketMask) {
    int b = blockIdx.y;
    if (selAll[b]) return;
    int ns = nS[b], ne = nE[b];
    unsigned pref = P[b];
    const int* si = sIdx + b * NT;
    const float* sv = sVal + b * NT;
    const int* ei = eIdx + b * NT;
    const float* ev = eVal + b * NT;
    unsigned* h = histLevel + b * 2048;

    __shared__ unsigned shist[2048];
    for (int c = threadIdx.x; c < 2048; c += 256) shist[c] = 0u;
    __syncthreads();

    for (int i = blockIdx.x; i < ns; i += gridDim.x) {
        int s = si[i];
        float svi = sv[i];
        for (int j = threadIdx.x; j < ne; j += 256) {
            int e = ei[j];
            if (e < s) continue;
            unsigned bits = __float_as_uint(svi * ev[j]);
            if ((bits & prefMask) != pref) continue;
            atomicAdd(&shist[(bits >> shift) & bucketMask], 1u);
        }
    }
    __syncthreads();
    for (int c = threadIdx.x; c < 2048; c += 256) {
        unsigned v = shist[c];
        if (v) atomicAdd(&h[c], v);
    }
}

// Descending scan over one level's histogram: find bucket where the
// cumulative count crosses `need`, extend prefix, update need.
__global__ void k_scan(const unsigned* __restrict__ histLevel, int level, int shift,
                       int buckets, int* selAll, unsigned* P, int* need) {
    int b = blockIdx.x;
    if (level > 0 && selAll[b]) return;
    const unsigned* h = histLevel + b * 2048;

    __shared__ int chunkSum[256];
    int chunk = buckets / 256;   // 8, 8, or 4
    int base = threadIdx.x * chunk;
    int sum = 0;
    for (int c = 0; c < chunk; c++) sum += (int)h[base + c];
    chunkSum[threadIdx.x] = sum;
    __syncthreads();

    if (threadIdx.x == 0) {
        int nd = (level == 0) ? KPROP : need[b];
        int acc = 0;
        int tchunk = -1;
        for (int t = 255; t >= 0; t--) {
            if (acc + chunkSum[t] >= nd) { tchunk = t; break; }
            acc += chunkSum[t];
        }
        if (tchunk < 0) {
            selAll[b] = 1;     // fewer than K valid pairs (level 0 only)
        } else {
            int found = -1;
            for (int c = tchunk * chunk + chunk - 1; c >= tchunk * chunk; c--) {
                int cnt = (int)h[c];
                if (acc + cnt >= nd) { found = c; break; }
                acc += cnt;
            }
            if (found < 0) { selAll[b] = 1; }   // defensive; cannot happen
            else {
                P[b] |= ((unsigned)found) << shift;
                need[b] = nd - acc;             // in [1, cnt[found]]
            }
        }
    }
}

// Write 1.0 for all pairs strictly above threshold V; collect ties (== V).
__global__ void k_scatter(const int* __restrict__ nS, const int* __restrict__ nE,
                          const int* __restrict__ sIdx, const float* __restrict__ sVal,
                          const int* __restrict__ eIdx, const float* __restrict__ eVal,
                          const int* __restrict__ selAll, const unsigned* __restrict__ P,
                          float* __restrict__ out, int* tieCnt, int* tie) {
    int b = blockIdx.y;
    int ns = nS[b], ne = nE[b];
    int all = selAll[b];
    unsigned V = P[b];
    const int* si = sIdx + b * NT;
    const float* sv = sVal + b * NT;
    const int* ei = eIdx + b * NT;
    const float* ev = eVal + b * NT;

    for (int i = blockIdx.x; i < ns; i += gridDim.x) {
        int s = si[i];
        float svi = sv[i];
        for (int j = threadIdx.x; j < ne; j += 256) {
            int e = ei[j];
            if (e < s) continue;
            unsigned bits = __float_as_uint(svi * ev[j]);
            if (all || bits > V) {
                out[((size_t)b * NT + (e - s)) * NT + s] = 1.0f;
            } else if (bits == V) {
                int pos = atomicAdd(tieCnt + b, 1);
                if (pos < TIE_CAP) tie[b * TIE_CAP + pos] = s * NT + e;
            }
        }
    }
}

// Among score == V, keep the `need` smallest flat indices (top_k tie order).
__global__ void k_ties(const int* __restrict__ selAll, const int* __restrict__ need,
                       const int* __restrict__ tieCnt, const int* __restrict__ tie,
                       float* __restrict__ out) {
    int b = blockIdx.x;
    if (selAll[b]) return;
    int n = min(tieCnt[b], TIE_CAP);
    int nd = need[b];
    const int* tl = tie + b * TIE_CAP;
    for (int k = threadIdx.x; k < n; k += blockDim.x) {
        int flat = tl[k];
        int rank = 0;
        for (int j = 0; j < n; j++) rank += (tl[j] < flat) ? 1 : 0;
        if (rank < nd) {
            int s = flat >> 11;            // NT = 2048
            int e = flat & (NT - 1);
            out[((size_t)b * NT + (e - s)) * NT + s] = 1.0f;
        }
    }
}

extern "C" void kernel_launch(void* const* d_in, const int* in_sizes, int n_in,
                              void* d_out, int out_size, void* d_ws, size_t ws_size,
                              hipStream_t stream) {
    const float* start = (const float*)d_in[0];
    const float* end   = (const float*)d_in[1];
    // d_in[2] (actionness) is unused by the reference.
    float* out = (float*)d_out;
    char* ws = (char*)d_ws;

    int*      nS     = (int*)     (ws + 0);
    int*      nE     = (int*)     (ws + 64);
    int*      selAll = (int*)     (ws + 128);
    unsigned* P      = (unsigned*)(ws + 192);
    int*      need   = (int*)     (ws + 256);
    int*      tieCnt = (int*)     (ws + 320);
    unsigned* hist   = (unsigned*)(ws + 512);
    int*      sIdx   = (int*)     (ws + 393728);
    float*    sVal   = (float*)   (ws + 524800);
    int*      eIdx   = (int*)     (ws + 655872);
    float*    eVal   = (float*)   (ws + 786944);
    int*      tie    = (int*)     (ws + 918016);

    // 0) zero the 256 MiB output ourselves (rocclr fill was 4x write-amplified)
    int n4 = out_size / 4;                       // 16,777,216 float4s
    k_fill<<<2048, 256, 0, stream>>>((float4*)out, n4);

    // 1) anchor selection + compaction (+ zero hist & per-batch scalars)
    k_select<<<dim3(NB, 2), 256, 0, stream>>>(start, end, nS, nE, selAll, P, need, tieCnt,
                                              hist, sIdx, sVal, eIdx, eVal);

    // 2) exact radix-select of the K-th score (3 levels: bits [31:21],[20:10],[9:0])
    k_hist<<<dim3(64, NB), 256, 0, stream>>>(nS, nE, sIdx, sVal, eIdx, eVal, selAll, P,
                                             hist, 0u, 21, 2047u);
    k_scan<<<NB, 256, 0, stream>>>(hist, 0, 21, 2048, selAll, P, need);

    k_hist<<<dim3(64, NB), 256, 0, stream>>>(nS, nE, sIdx, sVal, eIdx, eVal, selAll, P,
                                             hist + NB * 2048, 0xFFE00000u, 10, 2047u);
    k_scan<<<NB, 256, 0, stream>>>(hist + NB * 2048, 1, 10, 2048, selAll, P, need);

    k_hist<<<dim3(64, NB), 256, 0, stream>>>(nS, nE, sIdx, sVal, eIdx, eVal, selAll, P,
                                             hist + 2 * NB * 2048, 0xFFFFFC00u, 0, 1023u);
    k_scan<<<NB, 256, 0, stream>>>(hist + 2 * NB * 2048, 2, 0, 1024, selAll, P, need);

    // 3) scatter winners; collect threshold ties
    k_scatter<<<dim3(64, NB), 256, 0, stream>>>(nS, nE, sIdx, sVal, eIdx, eVal, selAll, P,
                                                out, tieCnt, tie);
    // 4) resolve ties by smallest flat index (matches lax.top_k tie order)
    k_ties<<<NB, 256, 0, stream>>>(selAll, need, tieCnt, tie, out);
}